// Round 13
// baseline (295.669 us; speedup 1.0000x reference)
//
#include <hip/hip_runtime.h>
#include <hip/hip_bf16.h>
#include <math.h>

#define N_NODES 100000
#define N_EDGES 800000
#define NB_SCAN ((N_NODES + 1023) / 1024)   // 98

typedef __bf16 bf16x8 __attribute__((ext_vector_type(8)));
typedef float  f32x4  __attribute__((ext_vector_type(4)));

__device__ __forceinline__ float lrelu(float v){ return v > 0.f ? v : 0.2f*v; }
__device__ __forceinline__ float eluf(float v){ return v > 0.f ? v : (__expf(v) - 1.f); }

__device__ __forceinline__ unsigned short f2bf(float f){
    union { float f; unsigned u; } v; v.f = f;
    unsigned r = (v.u + 0x7fff + ((v.u >> 16) & 1)) >> 16;
    return (unsigned short)r;
}
__device__ __forceinline__ float bf2f(unsigned short u){
    union { unsigned u; float f; } v; v.u = ((unsigned)u) << 16;
    return v.f;
}

// ---------- setup: zero counts/lacc + convert both weight matrices ----------
__global__ __launch_bounds__(256) void setup_kernel(
    const float* __restrict__ W1, const float* __restrict__ W2,
    unsigned short* __restrict__ wt1, unsigned short* __restrict__ wt2,
    int* __restrict__ counts, float* __restrict__ lacc)
{
    int i = blockIdx.x*256 + threadIdx.x;
    if (i < N_NODES) counts[i] = 0;
    if (i < 4) lacc[i] = 0.f;
    if (i < 128*128){
        int n = i >> 7, k = i & 127;
        wt1[i] = f2bf(W1[k*128 + n]);
    }
    if (i < 112*128){
        int n = i >> 7, k = i & 127;
        wt2[i] = (n < 100) ? f2bf(W2[k*100 + n]) : (unsigned short)0;
    }
}

// ---------- CSR build: count + rank capture (coalesced rank store) ----------
__global__ __launch_bounds__(256) void count_kernel(const int* __restrict__ ei,
                                                    int* __restrict__ counts,
                                                    int* __restrict__ rank){
    int e = blockIdx.x*256 + threadIdx.x;
    if (e < N_EDGES){
        int d = ei[N_EDGES + e];
        rank[e] = atomicAdd(&counts[d], 1);
    }
}

__global__ __launch_bounds__(1024) void scan_blocks_kernel(const int* __restrict__ counts,
                                                           int* __restrict__ exoffs,
                                                           int* __restrict__ bsums){
    __shared__ int buf[1024];
    int t = threadIdx.x;
    int gid = blockIdx.x*1024 + t;
    int v = (gid < N_NODES) ? counts[gid] : 0;
    buf[t] = v;
    __syncthreads();
    #pragma unroll
    for (int off = 1; off < 1024; off <<= 1){
        int u = (t >= off) ? buf[t-off] : 0;
        __syncthreads();
        buf[t] += u;
        __syncthreads();
    }
    if (gid < N_NODES) exoffs[gid] = buf[t] - v;
    if (t == 1023) bsums[blockIdx.x] = buf[1023];
}

__global__ void scan_sums_kernel(const int* __restrict__ bsums, int* __restrict__ bpre){
    if (threadIdx.x == 0){
        int run = 0;
        #pragma unroll 4
        for (int b = 0; b < NB_SCAN; b++){ int v = bsums[b]; bpre[b] = run; run += v; }
    }
}

__global__ __launch_bounds__(1024) void scan_add_kernel(const int* __restrict__ exoffs,
                                                        const int* __restrict__ bpre,
                                                        int* __restrict__ offs){
    int gid = blockIdx.x*1024 + threadIdx.x;
    if (gid < N_NODES){
        offs[gid] = exoffs[gid] + bpre[blockIdx.x];
    }
    if (gid == 0) offs[N_NODES] = N_EDGES;
}

// ---------- scatter: atomic-free (slot = offs[d] + rank[e]) ----------
__global__ __launch_bounds__(256) void scatter_kernel(
    const int* __restrict__ ei, const int* __restrict__ offs, const int* __restrict__ rank,
    int* __restrict__ csr_src, int* __restrict__ csr_dst)
{
    int e = blockIdx.x*256 + threadIdx.x;
    if (e >= N_EDGES) return;
    int s = ei[e];
    int d = ei[N_EDGES + e];
    int slot = offs[d] + rank[e];
    csr_src[slot] = s;
    csr_dst[slot] = d;
}

// ---------- layer-1 edge weights (streaming, after gemm1) ----------
__global__ __launch_bounds__(256) void wk1_kernel(
    const int* __restrict__ csr_src, const int* __restrict__ csr_dst,
    const float* __restrict__ as1, const float* __restrict__ ad1,
    unsigned short* __restrict__ w1bf)
{
    int e = blockIdx.x*256 + threadIdx.x;
    if (e >= N_EDGES) return;
    int s = csr_src[e];
    int d = csr_dst[e];
    const f32x4* ap = (const f32x4*)(as1 + s*8);
    const f32x4* dp = (const f32x4*)(ad1 + d*8);
    f32x4 a0 = ap[0], a1 = ap[1];
    f32x4 d0 = dp[0], d1 = dp[1];
    ushort4 o0, o1;
    o0.x = f2bf(__expf(lrelu(a0[0]+d0[0])));
    o0.y = f2bf(__expf(lrelu(a0[1]+d0[1])));
    o0.z = f2bf(__expf(lrelu(a0[2]+d0[2])));
    o0.w = f2bf(__expf(lrelu(a0[3]+d0[3])));
    o1.x = f2bf(__expf(lrelu(a1[0]+d1[0])));
    o1.y = f2bf(__expf(lrelu(a1[1]+d1[1])));
    o1.z = f2bf(__expf(lrelu(a1[2]+d1[2])));
    o1.w = f2bf(__expf(lrelu(a1[3]+d1[3])));
    *(ushort4*)&w1bf[(size_t)e*8]     = o0;
    *(ushort4*)&w1bf[(size_t)e*8 + 4] = o1;
}

// ---------- layer-2 edge weights (streaming, after gemm2) ----------
__global__ __launch_bounds__(256) void wk2_kernel(
    const int* __restrict__ csr_src, const int* __restrict__ csr_dst,
    const float* __restrict__ as2, const float* __restrict__ ad2,
    unsigned short* __restrict__ w2bf)
{
    int e = blockIdx.x*256 + threadIdx.x;
    if (e >= N_EDGES) return;
    int s = csr_src[e];
    int d = csr_dst[e];
    const float* ap = as2 + s*10;
    const float* dp = ad2 + d*10;
    unsigned short o[10];
    #pragma unroll
    for (int h = 0; h < 10; h++) o[h] = f2bf(__expf(lrelu(ap[h] + dp[h])));
    ushort2* wp = (ushort2*)&w2bf[(size_t)e*10];
    #pragma unroll
    for (int h = 0; h < 5; h++) wp[h] = make_ushort2(o[2*h], o[2*h+1]);
}

// ---------- GEMM1 (MFMA, 32-row tile, 2x2 waves): h1 = bf16(x) @ bf16(W1) + alpha1 ----------
__global__ __launch_bounds__(256) void gemm1_mfma(
    const float* __restrict__ x, const unsigned short* __restrict__ wt1,
    const float* __restrict__ a_src, const float* __restrict__ a_dst,
    unsigned short* __restrict__ h1bf, float* __restrict__ as1, float* __restrict__ ad1)
{
    __shared__ unsigned short Al[32*128];   // 8 KB, XOR-swizzled
    __shared__ unsigned short Bl[128*128];  // 32 KB, XOR-swizzled (rows = n of W^T)
    int t = threadIdx.x;
    int row0 = blockIdx.x*32;

    #pragma unroll
    for (int i = 0; i < 2; i++){
        int idx = (i*256 + t)*8;
        int r = idx >> 7, c = idx & 127;
        int grow = row0 + r;
        bf16x8 v;
        if (grow < N_NODES){
            const float4* p = (const float4*)(x + (size_t)grow*128 + c);
            float4 f0 = p[0], f1 = p[1];
            v[0]=(__bf16)f0.x; v[1]=(__bf16)f0.y; v[2]=(__bf16)f0.z; v[3]=(__bf16)f0.w;
            v[4]=(__bf16)f1.x; v[5]=(__bf16)f1.y; v[6]=(__bf16)f1.z; v[7]=(__bf16)f1.w;
        } else {
            #pragma unroll
            for (int j = 0; j < 8; j++) v[j] = (__bf16)0.f;
        }
        int byte = (r*256 + c*2) ^ ((r&7)<<4);
        *(bf16x8*)((char*)Al + byte) = v;
    }
    #pragma unroll
    for (int i = 0; i < 8; i++){
        int idx = (i*256 + t)*8;
        int n = idx >> 7, c = idx & 127;
        bf16x8 v = *(const bf16x8*)(wt1 + n*128 + c);
        int byte = (n*256 + c*2) ^ ((n&7)<<4);
        *(bf16x8*)((char*)Bl + byte) = v;
    }
    __syncthreads();

    int wv = t >> 6, l = t & 63;
    int wm = wv >> 1, wn = wv & 1;
    int lr = l & 15, lg = l >> 4;
    bf16x8 af[4];
    #pragma unroll
    for (int ks = 0; ks < 4; ks++){
        int r = wm*16 + lr;
        int byte = (r*256 + (ks*32 + lg*8)*2) ^ ((r&7)<<4);
        af[ks] = *(const bf16x8*)((const char*)Al + byte);
    }
    f32x4 acc[4];
    #pragma unroll
    for (int nt = 0; nt < 4; nt++){
        acc[nt] = (f32x4){0.f,0.f,0.f,0.f};
        #pragma unroll
        for (int ks = 0; ks < 4; ks++){
            int n = wn*64 + nt*16 + lr;
            int byte = (n*256 + (ks*32 + lg*8)*2) ^ ((n&7)<<4);
            bf16x8 bfv = *(const bf16x8*)((const char*)Bl + byte);
            acc[nt] = __builtin_amdgcn_mfma_f32_16x16x32_bf16(af[ks], bfv, acc[nt], 0, 0, 0);
        }
    }
    int orow_base = row0 + wm*16 + lg*4;
    #pragma unroll
    for (int nt = 0; nt < 4; nt++){
        int colb = wn*64 + nt*16;
        int head = colb >> 4;
        float avs = a_src[colb + lr];
        float avd = a_dst[colb + lr];
        #pragma unroll
        for (int r = 0; r < 4; r++){
            int grow = orow_base + r;
            float v = acc[nt][r];
            if (grow < N_NODES) h1bf[(size_t)grow*128 + colb + lr] = f2bf(v);
            float ps = v*avs, pd = v*avd;
            ps += __shfl_xor(ps,1); ps += __shfl_xor(ps,2); ps += __shfl_xor(ps,4); ps += __shfl_xor(ps,8);
            pd += __shfl_xor(pd,1); pd += __shfl_xor(pd,2); pd += __shfl_xor(pd,4); pd += __shfl_xor(pd,8);
            if (lr == 0 && grow < N_NODES){
                as1[grow*8 + head] = ps;
                ad1[grow*8 + head] = pd;
            }
        }
    }
}

// ---------- agg layer1: one wave per dst; 8-deep gathers, 32-bit pre-scaled offsets ----------
__global__ __launch_bounds__(256) void agg1_kernel(
    const int* __restrict__ offs, const int* __restrict__ csr_src,
    const unsigned short* __restrict__ w1bf,
    const unsigned short* __restrict__ h1bf, const float* __restrict__ b1,
    float* __restrict__ emb1_out /* d_out + 1 */)
{
    int wave = threadIdx.x >> 6;
    int lane = threadIdx.x & 63;
    int d = blockIdx.x*4 + wave;
    if (d >= N_NODES) return;
    int h = lane >> 3;
    int col = 2*lane;
    const char* h1base = (const char*)h1bf;
    unsigned coff = (unsigned)(4*lane);    // byte offset of col within a 256 B row
    int e0 = offs[d], e1 = offs[d+1];
    float acc0 = 0.f, acc1 = 0.f, wsum = 0.f;

    for (int base = e0; base < e1; base += 64){
        int ii = base + lane;
        unsigned svb = (ii < e1) ? (unsigned)csr_src[ii]*256u : 0u;   // row byte offset
        int n = min(64, e1 - base);
        int nf = n & ~7;
        int i = 0;
        for (; i < nf; i += 8){               // full groups: no mask
            const unsigned short* wp = w1bf + (size_t)(base + i)*8 + h;
            unsigned bj[8]; unsigned hj[8];
            #pragma unroll
            for (int j = 0; j < 8; j++) bj[j] = __shfl(svb, i+j);
            #pragma unroll
            for (int j = 0; j < 8; j++) hj[j] = *(const unsigned*)(h1base + (bj[j] + coff));
            #pragma unroll
            for (int j = 0; j < 8; j++){
                float w = bf2f(wp[j*8]);
                acc0 += w*bf2f((unsigned short)hj[j]);
                acc1 += w*bf2f((unsigned short)(hj[j]>>16));
                wsum += w;
            }
        }
        if (i < n){                            // tail group: mask w only
            const unsigned short* wp = w1bf + (size_t)(base + i)*8 + h;
            unsigned bj[8]; unsigned hj[8];
            #pragma unroll
            for (int j = 0; j < 8; j++) bj[j] = __shfl(svb, i+j);
            #pragma unroll
            for (int j = 0; j < 8; j++) hj[j] = *(const unsigned*)(h1base + (bj[j] + coff));
            #pragma unroll
            for (int j = 0; j < 8; j++){
                float w = (i + j < n) ? bf2f(wp[j*8]) : 0.f;
                acc0 += w*bf2f((unsigned short)hj[j]);
                acc1 += w*bf2f((unsigned short)(hj[j]>>16));
                wsum += w;
            }
        }
    }
    float inv = 1.f/(wsum + 1e-16f);
    emb1_out[(size_t)d*128 + col]     = acc0*inv + b1[col];
    emb1_out[(size_t)d*128 + col + 1] = acc1*inv + b1[col+1];
}

// ---------- GEMM2 (MFMA, 32-row tile, 2x2 waves): h2 = bf16(elu(emb1)) @ bf16(W2) + alpha2 ----------
__global__ __launch_bounds__(256) void gemm2_mfma(
    const float* __restrict__ emb1g /* d_out+1 */, const unsigned short* __restrict__ wt2,
    const float* __restrict__ a_src2, const float* __restrict__ a_dst2,
    unsigned short* __restrict__ h2bf, float* __restrict__ as2, float* __restrict__ ad2)
{
    __shared__ __align__(16) char smem[36864];          // 8K (Al) + 28K (Bl)
    unsigned short* Al = (unsigned short*)smem;         // 32*128
    unsigned short* Bl = Al + 32*128;                   // 112*128
    float* Hl = (float*)smem;                           // reused: 32*113 f32

    int t = threadIdx.x;
    int row0 = blockIdx.x*32;

    #pragma unroll
    for (int i = 0; i < 2; i++){
        int idx = (i*256 + t)*8;
        int r = idx >> 7, c = idx & 127;
        int grow = row0 + r;
        bf16x8 v;
        if (grow < N_NODES){
            const float4* p = (const float4*)(emb1g + (size_t)grow*128 + c);
            float4 f0 = p[0], f1 = p[1];
            v[0]=(__bf16)eluf(f0.x); v[1]=(__bf16)eluf(f0.y); v[2]=(__bf16)eluf(f0.z); v[3]=(__bf16)eluf(f0.w);
            v[4]=(__bf16)eluf(f1.x); v[5]=(__bf16)eluf(f1.y); v[6]=(__bf16)eluf(f1.z); v[7]=(__bf16)eluf(f1.w);
        } else {
            #pragma unroll
            for (int j = 0; j < 8; j++) v[j] = (__bf16)0.f;
        }
        int byte = (r*256 + c*2) ^ ((r&7)<<4);
        *(bf16x8*)((char*)Al + byte) = v;
    }
    #pragma unroll
    for (int i = 0; i < 7; i++){
        int idx = (i*256 + t)*8;
        int n = idx >> 7, c = idx & 127;
        bf16x8 v = *(const bf16x8*)(wt2 + n*128 + c);
        int byte = (n*256 + c*2) ^ ((n&7)<<4);
        *(bf16x8*)((char*)Bl + byte) = v;
    }
    __syncthreads();

    int wv = t >> 6, l = t & 63;
    int wm = wv >> 1, wn = wv & 1;
    int lr = l & 15, lg = l >> 4;
    bf16x8 af[4];
    #pragma unroll
    for (int ks = 0; ks < 4; ks++){
        int r = wm*16 + lr;
        int byte = (r*256 + (ks*32 + lg*8)*2) ^ ((r&7)<<4);
        af[ks] = *(const bf16x8*)((const char*)Al + byte);
    }
    int ntmax = wn ? 3 : 4;
    f32x4 acc[4];
    for (int nt = 0; nt < ntmax; nt++){
        acc[nt] = (f32x4){0.f,0.f,0.f,0.f};
        #pragma unroll
        for (int ks = 0; ks < 4; ks++){
            int n = wn*64 + nt*16 + lr;
            int byte = (n*256 + (ks*32 + lg*8)*2) ^ ((n&7)<<4);
            bf16x8 bfv = *(const bf16x8*)((const char*)Bl + byte);
            acc[nt] = __builtin_amdgcn_mfma_f32_16x16x32_bf16(af[ks], bfv, acc[nt], 0, 0, 0);
        }
    }
    int orow_base = row0 + wm*16 + lg*4;
    for (int nt = 0; nt < ntmax; nt++){
        int col = wn*64 + nt*16 + lr;
        if (col < 100){
            #pragma unroll
            for (int r = 0; r < 4; r++){
                int grow = orow_base + r;
                if (grow < N_NODES) h2bf[(size_t)grow*100 + col] = f2bf(acc[nt][r]);
            }
        }
    }
    __syncthreads();
    for (int nt = 0; nt < ntmax; nt++){
        int col = wn*64 + nt*16 + lr;
        int rbase = wm*16 + lg*4;
        #pragma unroll
        for (int r = 0; r < 4; r++) Hl[(rbase + r)*113 + col] = acc[nt][r];
    }
    __syncthreads();
    for (int task = t; task < 320; task += 256){
        int row = task/10, h = task - row*10;
        int grow = row0 + row;
        if (grow < N_NODES){
            const float* p = &Hl[row*113 + h*10];
            float s = 0.f, dd = 0.f;
            #pragma unroll
            for (int c = 0; c < 10; c++){
                float v = p[c];
                s  += v*a_src2[h*10 + c];
                dd += v*a_dst2[h*10 + c];
            }
            as2[grow*10 + h] = s;
            ad2[grow*10 + h] = dd;
        }
    }
}

// ---------- agg layer2: one wave per dst; 8-deep gathers, 32-bit pre-scaled offsets ----------
__global__ __launch_bounds__(256) void agg2_kernel(
    const int* __restrict__ offs, const int* __restrict__ csr_src,
    const unsigned short* __restrict__ w2bf,
    const unsigned short* __restrict__ h2bf, const float* __restrict__ b2,
    float* __restrict__ emb2_out)
{
    __shared__ float sval[4][100];
    int wv = threadIdx.x >> 6;
    int lane = threadIdx.x & 63;
    int d = blockIdx.x*4 + wv;
    if (d >= N_NODES) return;
    int c0 = 2*lane;
    bool act = lane < 50;
    int h = lane/5; if (h > 9) h = 9;
    const char* h2base = (const char*)h2bf;
    unsigned coff = (unsigned)(4*lane);
    int e0 = offs[d], e1 = offs[d+1];
    float acc0 = 0.f, acc1 = 0.f, wsum = 0.f;

    for (int base = e0; base < e1; base += 64){
        int ii = base + lane;
        unsigned svb = (ii < e1) ? (unsigned)csr_src[ii]*200u : 0u;   // row byte offset
        int n = min(64, e1 - base);
        int nf = n & ~7;
        int i = 0;
        for (; i < nf; i += 8){
            const unsigned short* wp = w2bf + (size_t)(base + i)*10 + h;
            unsigned bj[8]; unsigned vj[8];
            #pragma unroll
            for (int j = 0; j < 8; j++) bj[j] = __shfl(svb, i+j);
            #pragma unroll
            for (int j = 0; j < 8; j++) vj[j] = act ? *(const unsigned*)(h2base + (bj[j] + coff)) : 0u;
            #pragma unroll
            for (int j = 0; j < 8; j++){
                float w = bf2f(wp[j*10]);
                acc0 += w*bf2f((unsigned short)vj[j]);
                acc1 += w*bf2f((unsigned short)(vj[j]>>16));
                wsum += w;
            }
        }
        if (i < n){
            const unsigned short* wp = w2bf + (size_t)(base + i)*10 + h;
            unsigned bj[8]; unsigned vj[8];
            #pragma unroll
            for (int j = 0; j < 8; j++) bj[j] = __shfl(svb, i+j);
            #pragma unroll
            for (int j = 0; j < 8; j++) vj[j] = act ? *(const unsigned*)(h2base + (bj[j] + coff)) : 0u;
            #pragma unroll
            for (int j = 0; j < 8; j++){
                float w = (i + j < n) ? bf2f(wp[j*10]) : 0.f;
                acc0 += w*bf2f((unsigned short)vj[j]);
                acc1 += w*bf2f((unsigned short)(vj[j]>>16));
                wsum += w;
            }
        }
    }
    if (act){
        float inv = 1.f/(wsum + 1e-16f);
        sval[wv][c0]   = acc0*inv;
        sval[wv][c0+1] = acc1*inv;
    }
    __syncthreads();
    if (lane < 10){
        float s = 0.f;
        #pragma unroll
        for (int hh = 0; hh < 10; hh++) s += sval[wv][hh*10 + lane];
        emb2_out[(size_t)d*10 + lane] = s*0.1f + b2[lane];
    }
}

// ---------- loss ----------
__global__ __launch_bounds__(256) void loss_kernel(
    const float* __restrict__ emb2, const int* __restrict__ labels,
    const int* __restrict__ mask, float* __restrict__ acc)
{
    int i = blockIdx.x*256 + threadIdx.x;
    float num = 0.f, den = 0.f;
    if (i < N_NODES && mask[i] != 0){
        const float* v = emb2 + (size_t)i*10;
        float m = v[0];
        #pragma unroll
        for (int c = 1; c < 10; c++) m = fmaxf(m, v[c]);
        float s = 0.f;
        #pragma unroll
        for (int c = 0; c < 10; c++) s += __expf(v[c]-m);
        float lse = m + __logf(s);
        num = lse - v[labels[i]];
        den = 1.f;
    }
    #pragma unroll
    for (int o = 32; o >= 1; o >>= 1){ num += __shfl_down(num, o); den += __shfl_down(den, o); }
    if ((threadIdx.x & 63) == 0){
        atomicAdd(&acc[0], num);
        atomicAdd(&acc[1], den);
    }
}

__global__ void finalize_kernel(const float* __restrict__ acc, float* __restrict__ out0){
    out0[0] = acc[0]/acc[1];
}

extern "C" void kernel_launch(void* const* d_in, const int* in_sizes, int n_in,
                              void* d_out, int out_size, void* d_ws, size_t ws_size,
                              hipStream_t stream) {
    const float* x      = (const float*)d_in[0];
    const int*   ei     = (const int*)d_in[1];
    const int*   labels = (const int*)d_in[2];
    const int*   mask   = (const int*)d_in[3];
    const float* W1     = (const float*)d_in[4];
    const float* a_src1 = (const float*)d_in[5];
    const float* a_dst1 = (const float*)d_in[6];
    const float* b1     = (const float*)d_in[7];
    const float* W2     = (const float*)d_in[8];
    const float* a_src2 = (const float*)d_in[9];
    const float* a_dst2 = (const float*)d_in[10];
    const float* b2     = (const float*)d_in[11];

    float* out  = (float*)d_out;
    float* emb1 = out + 1;                       // [N,128]
    float* emb2 = out + 1 + (size_t)N_NODES*128; // [N,10]

    unsigned short* h1bf = (unsigned short*)d_ws;              // N*128 bf16
    unsigned short* h2bf = h1bf + (size_t)N_NODES*128;         // N*100 bf16
    unsigned short* w1bf = h2bf + (size_t)N_NODES*100;         // (E+8)*8 bf16
    unsigned short* w2bf = w1bf + (size_t)(N_EDGES+8)*8;       // (E+8)*10 bf16
    float* as1  = (float*)(w2bf + (size_t)(N_EDGES+8)*10);
    float* ad1  = as1 + (size_t)N_NODES*8;
    float* as2  = ad1 + (size_t)N_NODES*8;
    float* ad2  = as2 + (size_t)N_NODES*10;
    float* lacc = ad2 + (size_t)N_NODES*10;  // 4 floats
    int* counts = (int*)(lacc + 4);          // N
    int* offs   = counts + N_NODES;          // N+1
    int* rank   = offs + N_NODES + 1;        // E
    int* csr    = rank + N_EDGES;            // E
    int* csrd   = csr + N_EDGES;             // E
    int* exoffs = csrd + N_EDGES;            // N
    int* bsums  = exoffs + N_NODES;          // NB_SCAN
    int* bpre   = bsums + NB_SCAN;           // NB_SCAN
    unsigned short* wt1 = (unsigned short*)(bpre + NB_SCAN);   // 128*128 bf16
    unsigned short* wt2 = wt1 + 128*128;                       // 112*128 bf16

    setup_kernel<<<(N_NODES+255)/256, 256, 0, stream>>>(W1, W2, wt1, wt2, counts, lacc);
    count_kernel<<<N_EDGES/256, 256, 0, stream>>>(ei, counts, rank);
    scan_blocks_kernel<<<NB_SCAN, 1024, 0, stream>>>(counts, exoffs, bsums);
    scan_sums_kernel<<<1, 64, 0, stream>>>(bsums, bpre);
    scan_add_kernel<<<NB_SCAN, 1024, 0, stream>>>(exoffs, bpre, offs);
    scatter_kernel<<<N_EDGES/256, 256, 0, stream>>>(ei, offs, rank, csr, csrd);

    int gblocks = (N_NODES + 31)/32;  // 3125
    gemm1_mfma<<<gblocks, 256, 0, stream>>>(x, wt1, a_src1, a_dst1, h1bf, as1, ad1);
    wk1_kernel<<<N_EDGES/256, 256, 0, stream>>>(csr, csrd, as1, ad1, w1bf);
    agg1_kernel<<<(N_NODES + 3)/4, 256, 0, stream>>>(offs, csr, w1bf, h1bf, b1, emb1);
    gemm2_mfma<<<gblocks, 256, 0, stream>>>(emb1, wt2, a_src2, a_dst2, h2bf, as2, ad2);
    wk2_kernel<<<N_EDGES/256, 256, 0, stream>>>(csr, csrd, as2, ad2, w2bf);
    agg2_kernel<<<(N_NODES + 3)/4, 256, 0, stream>>>(offs, csr, w2bf, h2bf, b2, emb2);
    loss_kernel<<<(N_NODES+255)/256, 256, 0, stream>>>(emb2, labels, mask, lacc);
    finalize_kernel<<<1, 1, 0, stream>>>(lacc, out);
}

// Round 14
// 276.672 us; speedup vs baseline: 1.0687x; 1.0687x over previous
//
#include <hip/hip_runtime.h>
#include <hip/hip_bf16.h>
#include <math.h>

#define N_NODES 100000
#define N_EDGES 800000
#define NB_SCAN ((N_NODES + 1023) / 1024)   // 98
#define GB1 ((N_NODES + 31)/32)             // 3125 gemm1 blocks
#define SB  ((N_EDGES + 255)/256)           // 3125 scatter blocks

typedef __bf16 bf16x8 __attribute__((ext_vector_type(8)));
typedef float  f32x4  __attribute__((ext_vector_type(4)));

__device__ __forceinline__ float lrelu(float v){ return v > 0.f ? v : 0.2f*v; }
__device__ __forceinline__ float eluf(float v){ return v > 0.f ? v : (__expf(v) - 1.f); }

__device__ __forceinline__ unsigned short f2bf(float f){
    union { float f; unsigned u; } v; v.f = f;
    unsigned r = (v.u + 0x7fff + ((v.u >> 16) & 1)) >> 16;
    return (unsigned short)r;
}
__device__ __forceinline__ float bf2f(unsigned short u){
    union { unsigned u; float f; } v; v.u = ((unsigned)u) << 16;
    return v.f;
}

// ---------- setup: zero counts/lacc + convert both weight matrices ----------
__global__ __launch_bounds__(256) void setup_kernel(
    const float* __restrict__ W1, const float* __restrict__ W2,
    unsigned short* __restrict__ wt1, unsigned short* __restrict__ wt2,
    int* __restrict__ counts, float* __restrict__ lacc)
{
    int i = blockIdx.x*256 + threadIdx.x;
    if (i < N_NODES) counts[i] = 0;
    if (i < 4) lacc[i] = 0.f;
    if (i < 128*128){
        int n = i >> 7, k = i & 127;
        wt1[i] = f2bf(W1[k*128 + n]);
    }
    if (i < 112*128){
        int n = i >> 7, k = i & 127;
        wt2[i] = (n < 100) ? f2bf(W2[k*100 + n]) : (unsigned short)0;
    }
}

// ---------- CSR build: count + rank capture (coalesced rank store) ----------
__global__ __launch_bounds__(256) void count_kernel(const int* __restrict__ ei,
                                                    int* __restrict__ counts,
                                                    int* __restrict__ rank){
    int e = blockIdx.x*256 + threadIdx.x;
    if (e < N_EDGES){
        int d = ei[N_EDGES + e];
        rank[e] = atomicAdd(&counts[d], 1);
    }
}

__global__ __launch_bounds__(1024) void scan_blocks_kernel(const int* __restrict__ counts,
                                                           int* __restrict__ exoffs,
                                                           int* __restrict__ bsums){
    __shared__ int buf[1024];
    int t = threadIdx.x;
    int gid = blockIdx.x*1024 + t;
    int v = (gid < N_NODES) ? counts[gid] : 0;
    buf[t] = v;
    __syncthreads();
    #pragma unroll
    for (int off = 1; off < 1024; off <<= 1){
        int u = (t >= off) ? buf[t-off] : 0;
        __syncthreads();
        buf[t] += u;
        __syncthreads();
    }
    if (gid < N_NODES) exoffs[gid] = buf[t] - v;
    if (t == 1023) bsums[blockIdx.x] = buf[1023];
}

__global__ void scan_sums_kernel(const int* __restrict__ bsums, int* __restrict__ bpre){
    if (threadIdx.x == 0){
        int run = 0;
        #pragma unroll 4
        for (int b = 0; b < NB_SCAN; b++){ int v = bsums[b]; bpre[b] = run; run += v; }
    }
}

__global__ __launch_bounds__(1024) void scan_add_kernel(const int* __restrict__ exoffs,
                                                        const int* __restrict__ bpre,
                                                        int* __restrict__ offs){
    int gid = blockIdx.x*1024 + threadIdx.x;
    if (gid < N_NODES){
        offs[gid] = exoffs[gid] + bpre[blockIdx.x];
    }
    if (gid == 0) offs[N_NODES] = N_EDGES;
}

// ---------- FAT kernel: gemm1 (blocks 0..GB1-1)  ||  scatter (blocks GB1..GB1+SB-1) ----------
__global__ __launch_bounds__(256) void gemm1_scatter_kernel(
    const float* __restrict__ x, const unsigned short* __restrict__ wt1,
    const float* __restrict__ a_src, const float* __restrict__ a_dst,
    unsigned short* __restrict__ h1bf, float* __restrict__ as1, float* __restrict__ ad1,
    const int* __restrict__ ei, const int* __restrict__ offs, const int* __restrict__ rank,
    int* __restrict__ csr_src, int* __restrict__ csr_dst)
{
    __shared__ unsigned short Al[32*128];   // 8 KB, XOR-swizzled
    __shared__ unsigned short Bl[128*128];  // 32 KB, XOR-swizzled (rows = n of W^T)
    int t = threadIdx.x;

    if (blockIdx.x >= GB1){
        // ---- scatter part: atomic-free (slot = offs[d] + rank[e]) ----
        int e = (blockIdx.x - GB1)*256 + t;
        if (e < N_EDGES){
            int s = ei[e];
            int d = ei[N_EDGES + e];
            int slot = offs[d] + rank[e];
            csr_src[slot] = s;
            csr_dst[slot] = d;
        }
        return;
    }

    // ---- gemm1 part (32-row tile, 2x2 waves) ----
    int row0 = blockIdx.x*32;

    #pragma unroll
    for (int i = 0; i < 2; i++){
        int idx = (i*256 + t)*8;
        int r = idx >> 7, c = idx & 127;
        int grow = row0 + r;
        bf16x8 v;
        if (grow < N_NODES){
            const float4* p = (const float4*)(x + (size_t)grow*128 + c);
            float4 f0 = p[0], f1 = p[1];
            v[0]=(__bf16)f0.x; v[1]=(__bf16)f0.y; v[2]=(__bf16)f0.z; v[3]=(__bf16)f0.w;
            v[4]=(__bf16)f1.x; v[5]=(__bf16)f1.y; v[6]=(__bf16)f1.z; v[7]=(__bf16)f1.w;
        } else {
            #pragma unroll
            for (int j = 0; j < 8; j++) v[j] = (__bf16)0.f;
        }
        int byte = (r*256 + c*2) ^ ((r&7)<<4);
        *(bf16x8*)((char*)Al + byte) = v;
    }
    #pragma unroll
    for (int i = 0; i < 8; i++){
        int idx = (i*256 + t)*8;
        int n = idx >> 7, c = idx & 127;
        bf16x8 v = *(const bf16x8*)(wt1 + n*128 + c);
        int byte = (n*256 + c*2) ^ ((n&7)<<4);
        *(bf16x8*)((char*)Bl + byte) = v;
    }
    __syncthreads();

    int wv = t >> 6, l = t & 63;
    int wm = wv >> 1, wn = wv & 1;
    int lr = l & 15, lg = l >> 4;
    bf16x8 af[4];
    #pragma unroll
    for (int ks = 0; ks < 4; ks++){
        int r = wm*16 + lr;
        int byte = (r*256 + (ks*32 + lg*8)*2) ^ ((r&7)<<4);
        af[ks] = *(const bf16x8*)((const char*)Al + byte);
    }
    f32x4 acc[4];
    #pragma unroll
    for (int nt = 0; nt < 4; nt++){
        acc[nt] = (f32x4){0.f,0.f,0.f,0.f};
        #pragma unroll
        for (int ks = 0; ks < 4; ks++){
            int n = wn*64 + nt*16 + lr;
            int byte = (n*256 + (ks*32 + lg*8)*2) ^ ((n&7)<<4);
            bf16x8 bfv = *(const bf16x8*)((const char*)Bl + byte);
            acc[nt] = __builtin_amdgcn_mfma_f32_16x16x32_bf16(af[ks], bfv, acc[nt], 0, 0, 0);
        }
    }
    int orow_base = row0 + wm*16 + lg*4;
    #pragma unroll
    for (int nt = 0; nt < 4; nt++){
        int colb = wn*64 + nt*16;
        int head = colb >> 4;
        float avs = a_src[colb + lr];
        float avd = a_dst[colb + lr];
        #pragma unroll
        for (int r = 0; r < 4; r++){
            int grow = orow_base + r;
            float v = acc[nt][r];
            if (grow < N_NODES) h1bf[(size_t)grow*128 + colb + lr] = f2bf(v);
            float ps = v*avs, pd = v*avd;
            ps += __shfl_xor(ps,1); ps += __shfl_xor(ps,2); ps += __shfl_xor(ps,4); ps += __shfl_xor(ps,8);
            pd += __shfl_xor(pd,1); pd += __shfl_xor(pd,2); pd += __shfl_xor(pd,4); pd += __shfl_xor(pd,8);
            if (lr == 0 && grow < N_NODES){
                as1[grow*8 + head] = ps;
                ad1[grow*8 + head] = pd;
            }
        }
    }
}

// ---------- layer-1 edge weights (streaming, after gemm1) ----------
__global__ __launch_bounds__(256) void wk1_kernel(
    const int* __restrict__ csr_src, const int* __restrict__ csr_dst,
    const float* __restrict__ as1, const float* __restrict__ ad1,
    unsigned short* __restrict__ w1bf)
{
    int e = blockIdx.x*256 + threadIdx.x;
    if (e >= N_EDGES) return;
    int s = csr_src[e];
    int d = csr_dst[e];
    const f32x4* ap = (const f32x4*)(as1 + s*8);
    const f32x4* dp = (const f32x4*)(ad1 + d*8);
    f32x4 a0 = ap[0], a1 = ap[1];
    f32x4 d0 = dp[0], d1 = dp[1];
    ushort4 o0, o1;
    o0.x = f2bf(__expf(lrelu(a0[0]+d0[0])));
    o0.y = f2bf(__expf(lrelu(a0[1]+d0[1])));
    o0.z = f2bf(__expf(lrelu(a0[2]+d0[2])));
    o0.w = f2bf(__expf(lrelu(a0[3]+d0[3])));
    o1.x = f2bf(__expf(lrelu(a1[0]+d1[0])));
    o1.y = f2bf(__expf(lrelu(a1[1]+d1[1])));
    o1.z = f2bf(__expf(lrelu(a1[2]+d1[2])));
    o1.w = f2bf(__expf(lrelu(a1[3]+d1[3])));
    *(ushort4*)&w1bf[(size_t)e*8]     = o0;
    *(ushort4*)&w1bf[(size_t)e*8 + 4] = o1;
}

// ---------- layer-2 edge weights (streaming, after gemm2) ----------
__global__ __launch_bounds__(256) void wk2_kernel(
    const int* __restrict__ csr_src, const int* __restrict__ csr_dst,
    const float* __restrict__ as2, const float* __restrict__ ad2,
    unsigned short* __restrict__ w2bf)
{
    int e = blockIdx.x*256 + threadIdx.x;
    if (e >= N_EDGES) return;
    int s = csr_src[e];
    int d = csr_dst[e];
    const float* ap = as2 + s*10;
    const float* dp = ad2 + d*10;
    unsigned short o[10];
    #pragma unroll
    for (int h = 0; h < 10; h++) o[h] = f2bf(__expf(lrelu(ap[h] + dp[h])));
    ushort2* wp = (ushort2*)&w2bf[(size_t)e*10];
    #pragma unroll
    for (int h = 0; h < 5; h++) wp[h] = make_ushort2(o[2*h], o[2*h+1]);
}

// ---------- agg layer1: one wave per dst; masked 8-deep gathers (round-12 form) ----------
__global__ __launch_bounds__(256) void agg1_kernel(
    const int* __restrict__ offs, const int* __restrict__ csr_src,
    const unsigned short* __restrict__ w1bf,
    const unsigned short* __restrict__ h1bf, const float* __restrict__ b1,
    float* __restrict__ emb1_out /* d_out + 1 */)
{
    int wave = threadIdx.x >> 6;
    int lane = threadIdx.x & 63;
    int d = blockIdx.x*4 + wave;
    if (d >= N_NODES) return;
    int h = lane >> 3;
    int col = 2*lane;
    int e0 = offs[d], e1 = offs[d+1];
    float acc0 = 0.f, acc1 = 0.f, wsum = 0.f;

    for (int base = e0; base < e1; base += 64){
        int ii = base + lane;
        int sv = (ii < e1) ? csr_src[ii] : 0;
        int n = min(64, e1 - base);
        for (int i = 0; i < n; i += 8){
            const unsigned short* wp = w1bf + (size_t)(base + i)*8 + h;
            int sj[8]; unsigned hj[8];
            #pragma unroll
            for (int j = 0; j < 8; j++) sj[j] = __shfl(sv, i+j);
            #pragma unroll
            for (int j = 0; j < 8; j++) hj[j] = *(const unsigned*)(h1bf + (size_t)sj[j]*128 + col);
            #pragma unroll
            for (int j = 0; j < 8; j++){
                float w = bf2f(wp[j*8]);
                w = (i + j < n) ? w : 0.f;
                acc0 += w*bf2f((unsigned short)hj[j]);
                acc1 += w*bf2f((unsigned short)(hj[j]>>16));
                wsum += w;
            }
        }
    }
    float inv = 1.f/(wsum + 1e-16f);
    emb1_out[(size_t)d*128 + col]     = acc0*inv + b1[col];
    emb1_out[(size_t)d*128 + col + 1] = acc1*inv + b1[col+1];
}

// ---------- GEMM2 (MFMA, 32-row tile, 2x2 waves): h2 = bf16(elu(emb1)) @ bf16(W2) + alpha2 ----------
__global__ __launch_bounds__(256) void gemm2_mfma(
    const float* __restrict__ emb1g /* d_out+1 */, const unsigned short* __restrict__ wt2,
    const float* __restrict__ a_src2, const float* __restrict__ a_dst2,
    unsigned short* __restrict__ h2bf, float* __restrict__ as2, float* __restrict__ ad2)
{
    __shared__ __align__(16) char smem[36864];          // 8K (Al) + 28K (Bl)
    unsigned short* Al = (unsigned short*)smem;         // 32*128
    unsigned short* Bl = Al + 32*128;                   // 112*128
    float* Hl = (float*)smem;                           // reused: 32*113 f32

    int t = threadIdx.x;
    int row0 = blockIdx.x*32;

    #pragma unroll
    for (int i = 0; i < 2; i++){
        int idx = (i*256 + t)*8;
        int r = idx >> 7, c = idx & 127;
        int grow = row0 + r;
        bf16x8 v;
        if (grow < N_NODES){
            const float4* p = (const float4*)(emb1g + (size_t)grow*128 + c);
            float4 f0 = p[0], f1 = p[1];
            v[0]=(__bf16)eluf(f0.x); v[1]=(__bf16)eluf(f0.y); v[2]=(__bf16)eluf(f0.z); v[3]=(__bf16)eluf(f0.w);
            v[4]=(__bf16)eluf(f1.x); v[5]=(__bf16)eluf(f1.y); v[6]=(__bf16)eluf(f1.z); v[7]=(__bf16)eluf(f1.w);
        } else {
            #pragma unroll
            for (int j = 0; j < 8; j++) v[j] = (__bf16)0.f;
        }
        int byte = (r*256 + c*2) ^ ((r&7)<<4);
        *(bf16x8*)((char*)Al + byte) = v;
    }
    #pragma unroll
    for (int i = 0; i < 7; i++){
        int idx = (i*256 + t)*8;
        int n = idx >> 7, c = idx & 127;
        bf16x8 v = *(const bf16x8*)(wt2 + n*128 + c);
        int byte = (n*256 + c*2) ^ ((n&7)<<4);
        *(bf16x8*)((char*)Bl + byte) = v;
    }
    __syncthreads();

    int wv = t >> 6, l = t & 63;
    int wm = wv >> 1, wn = wv & 1;
    int lr = l & 15, lg = l >> 4;
    bf16x8 af[4];
    #pragma unroll
    for (int ks = 0; ks < 4; ks++){
        int r = wm*16 + lr;
        int byte = (r*256 + (ks*32 + lg*8)*2) ^ ((r&7)<<4);
        af[ks] = *(const bf16x8*)((const char*)Al + byte);
    }
    int ntmax = wn ? 3 : 4;
    f32x4 acc[4];
    for (int nt = 0; nt < ntmax; nt++){
        acc[nt] = (f32x4){0.f,0.f,0.f,0.f};
        #pragma unroll
        for (int ks = 0; ks < 4; ks++){
            int n = wn*64 + nt*16 + lr;
            int byte = (n*256 + (ks*32 + lg*8)*2) ^ ((n&7)<<4);
            bf16x8 bfv = *(const bf16x8*)((const char*)Bl + byte);
            acc[nt] = __builtin_amdgcn_mfma_f32_16x16x32_bf16(af[ks], bfv, acc[nt], 0, 0, 0);
        }
    }
    int orow_base = row0 + wm*16 + lg*4;
    for (int nt = 0; nt < ntmax; nt++){
        int col = wn*64 + nt*16 + lr;
        if (col < 100){
            #pragma unroll
            for (int r = 0; r < 4; r++){
                int grow = orow_base + r;
                if (grow < N_NODES) h2bf[(size_t)grow*100 + col] = f2bf(acc[nt][r]);
            }
        }
    }
    __syncthreads();
    for (int nt = 0; nt < ntmax; nt++){
        int col = wn*64 + nt*16 + lr;
        int rbase = wm*16 + lg*4;
        #pragma unroll
        for (int r = 0; r < 4; r++) Hl[(rbase + r)*113 + col] = acc[nt][r];
    }
    __syncthreads();
    for (int task = t; task < 320; task += 256){
        int row = task/10, h = task - row*10;
        int grow = row0 + row;
        if (grow < N_NODES){
            const float* p = &Hl[row*113 + h*10];
            float s = 0.f, dd = 0.f;
            #pragma unroll
            for (int c = 0; c < 10; c++){
                float v = p[c];
                s  += v*a_src2[h*10 + c];
                dd += v*a_dst2[h*10 + c];
            }
            as2[grow*10 + h] = s;
            ad2[grow*10 + h] = dd;
        }
    }
}

// ---------- agg layer2: one wave per dst; masked 8-deep gathers (round-12 form) ----------
__global__ __launch_bounds__(256) void agg2_kernel(
    const int* __restrict__ offs, const int* __restrict__ csr_src,
    const unsigned short* __restrict__ w2bf,
    const unsigned short* __restrict__ h2bf, const float* __restrict__ b2,
    float* __restrict__ emb2_out)
{
    __shared__ float sval[4][100];
    int wv = threadIdx.x >> 6;
    int lane = threadIdx.x & 63;
    int d = blockIdx.x*4 + wv;
    if (d >= N_NODES) return;
    int c0 = 2*lane;
    bool act = lane < 50;
    int h = lane/5; if (h > 9) h = 9;
    int e0 = offs[d], e1 = offs[d+1];
    float acc0 = 0.f, acc1 = 0.f, wsum = 0.f;

    for (int base = e0; base < e1; base += 64){
        int ii = base + lane;
        int sv = (ii < e1) ? csr_src[ii] : 0;
        int n = min(64, e1 - base);
        for (int i = 0; i < n; i += 8){
            const unsigned short* wp = w2bf + (size_t)(base + i)*10 + h;
            int sj[8]; unsigned vj[8];
            #pragma unroll
            for (int j = 0; j < 8; j++) sj[j] = __shfl(sv, i+j);
            #pragma unroll
            for (int j = 0; j < 8; j++) vj[j] = act ? *(const unsigned*)(h2bf + (size_t)sj[j]*100 + c0) : 0u;
            #pragma unroll
            for (int j = 0; j < 8; j++){
                float w = bf2f(wp[j*10]);
                w = (i + j < n) ? w : 0.f;
                acc0 += w*bf2f((unsigned short)vj[j]);
                acc1 += w*bf2f((unsigned short)(vj[j]>>16));
                wsum += w;
            }
        }
    }
    if (act){
        float inv = 1.f/(wsum + 1e-16f);
        sval[wv][c0]   = acc0*inv;
        sval[wv][c0+1] = acc1*inv;
    }
    __syncthreads();
    if (lane < 10){
        float s = 0.f;
        #pragma unroll
        for (int hh = 0; hh < 10; hh++) s += sval[wv][hh*10 + lane];
        emb2_out[(size_t)d*10 + lane] = s*0.1f + b2[lane];
    }
}

// ---------- loss ----------
__global__ __launch_bounds__(256) void loss_kernel(
    const float* __restrict__ emb2, const int* __restrict__ labels,
    const int* __restrict__ mask, float* __restrict__ acc)
{
    int i = blockIdx.x*256 + threadIdx.x;
    float num = 0.f, den = 0.f;
    if (i < N_NODES && mask[i] != 0){
        const float* v = emb2 + (size_t)i*10;
        float m = v[0];
        #pragma unroll
        for (int c = 1; c < 10; c++) m = fmaxf(m, v[c]);
        float s = 0.f;
        #pragma unroll
        for (int c = 0; c < 10; c++) s += __expf(v[c]-m);
        float lse = m + __logf(s);
        num = lse - v[labels[i]];
        den = 1.f;
    }
    #pragma unroll
    for (int o = 32; o >= 1; o >>= 1){ num += __shfl_down(num, o); den += __shfl_down(den, o); }
    if ((threadIdx.x & 63) == 0){
        atomicAdd(&acc[0], num);
        atomicAdd(&acc[1], den);
    }
}

__global__ void finalize_kernel(const float* __restrict__ acc, float* __restrict__ out0){
    out0[0] = acc[0]/acc[1];
}

extern "C" void kernel_launch(void* const* d_in, const int* in_sizes, int n_in,
                              void* d_out, int out_size, void* d_ws, size_t ws_size,
                              hipStream_t stream) {
    const float* x      = (const float*)d_in[0];
    const int*   ei     = (const int*)d_in[1];
    const int*   labels = (const int*)d_in[2];
    const int*   mask   = (const int*)d_in[3];
    const float* W1     = (const float*)d_in[4];
    const float* a_src1 = (const float*)d_in[5];
    const float* a_dst1 = (const float*)d_in[6];
    const float* b1     = (const float*)d_in[7];
    const float* W2     = (const float*)d_in[8];
    const float* a_src2 = (const float*)d_in[9];
    const float* a_dst2 = (const float*)d_in[10];
    const float* b2     = (const float*)d_in[11];

    float* out  = (float*)d_out;
    float* emb1 = out + 1;                       // [N,128]
    float* emb2 = out + 1 + (size_t)N_NODES*128; // [N,10]

    unsigned short* h1bf = (unsigned short*)d_ws;              // N*128 bf16
    unsigned short* h2bf = h1bf + (size_t)N_NODES*128;         // N*100 bf16
    unsigned short* w1bf = h2bf + (size_t)N_NODES*100;         // (E+8)*8 bf16
    unsigned short* w2bf = w1bf + (size_t)(N_EDGES+8)*8;       // (E+8)*10 bf16
    float* as1  = (float*)(w2bf + (size_t)(N_EDGES+8)*10);
    float* ad1  = as1 + (size_t)N_NODES*8;
    float* as2  = ad1 + (size_t)N_NODES*8;
    float* ad2  = as2 + (size_t)N_NODES*10;
    float* lacc = ad2 + (size_t)N_NODES*10;  // 4 floats
    int* counts = (int*)(lacc + 4);          // N
    int* offs   = counts + N_NODES;          // N+1
    int* rank   = offs + N_NODES + 1;        // E
    int* csr    = rank + N_EDGES;            // E
    int* csrd   = csr + N_EDGES;             // E
    int* exoffs = csrd + N_EDGES;            // N
    int* bsums  = exoffs + N_NODES;          // NB_SCAN
    int* bpre   = bsums + NB_SCAN;           // NB_SCAN
    unsigned short* wt1 = (unsigned short*)(bpre + NB_SCAN);   // 128*128 bf16
    unsigned short* wt2 = wt1 + 128*128;                       // 112*128 bf16

    setup_kernel<<<(N_NODES+255)/256, 256, 0, stream>>>(W1, W2, wt1, wt2, counts, lacc);
    count_kernel<<<SB, 256, 0, stream>>>(ei, counts, rank);
    scan_blocks_kernel<<<NB_SCAN, 1024, 0, stream>>>(counts, exoffs, bsums);
    scan_sums_kernel<<<1, 64, 0, stream>>>(bsums, bpre);
    scan_add_kernel<<<NB_SCAN, 1024, 0, stream>>>(exoffs, bpre, offs);

    // fat: gemm1 (blocks 0..GB1-1) || scatter (blocks GB1..GB1+SB-1)
    gemm1_scatter_kernel<<<GB1 + SB, 256, 0, stream>>>(
        x, wt1, a_src1, a_dst1, h1bf, as1, ad1,
        ei, offs, rank, csr, csrd);

    wk1_kernel<<<SB, 256, 0, stream>>>(csr, csrd, as1, ad1, w1bf);
    agg1_kernel<<<(N_NODES + 3)/4, 256, 0, stream>>>(offs, csr, w1bf, h1bf, b1, emb1);
    gemm2_mfma<<<GB1, 256, 0, stream>>>(emb1, wt2, a_src2, a_dst2, h2bf, as2, ad2);
    wk2_kernel<<<SB, 256, 0, stream>>>(csr, csrd, as2, ad2, w2bf);
    agg2_kernel<<<(N_NODES + 3)/4, 256, 0, stream>>>(offs, csr, w2bf, h2bf, b2, emb2);
    loss_kernel<<<(N_NODES+255)/256, 256, 0, stream>>>(emb2, labels, mask, lacc);
    finalize_kernel<<<1, 1, 0, stream>>>(lacc, out);
}